// Round 1
// 482.875 us; speedup vs baseline: 1.0060x; 1.0060x over previous
//
#include <hip/hip_runtime.h>

// RWKV WKV forward scan, chunk-parallel two-pass formulation.
// B=16, T=2048, D=1024, fp32.
//
// The per-(b,d) recurrence  a_t = ew_t*a + ek_t ; b_t = ew_t*b + ek_t*v_t
// is affine in (a,b). Over a chunk of L steps it composes to
//   a_out = P*a_in + A,  b_out = P*b_in + B,  P = prod(ew), A/B local sums.
// K1 computes (P,A,B) per (chain, chunk)  -> 16x more waves than the serial
// kernel (16 waves/CU instead of 1), hiding HBM latency with TLP.
// K3 folds the preceding chunk summaries (cheap, L2-hot) into a carry-in,
// then re-streams the chunk computing outputs.
//
// Traffic: inputs read twice (804 MB) + 134 MB write + 6 MB ws, vs the
// serial kernel's 536 MB @ 17% of peak BW (occupancy 2.87% = 1 wave/CU).

#define TT   2048
#define DD   1024
#define BB   16
#define BDCH (BB * DD)     // 16384 chains
#define NC   16            // chunks along T
#define LL   (TT / NC)     // 128 steps per chunk
#define NTH  256           // threads per block (4 waves)
#define UU   8             // register prefetch batch (double-buffered)

// ---------------------------------------------------------------------------
// K1: per-(chain, chunk) partials  P = prod exp(w), A, B  (zero init state)
// ---------------------------------------------------------------------------
__global__ __launch_bounds__(NTH) void wkv_part(const float* __restrict__ kg,
                                                const float* __restrict__ vg,
                                                const float* __restrict__ wg,
                                                float* __restrict__ wsP,
                                                float* __restrict__ wsA,
                                                float* __restrict__ wsB) {
    const int g  = blockIdx.x * NTH + threadIdx.x;   // chain id in [0, B*D)
    const int ch = blockIdx.y;                        // chunk id
    const size_t base = (size_t)(g >> 10) * (size_t)TT * DD
                      + (size_t)ch * LL * DD
                      + (size_t)(g & (DD - 1));
    const float* kp = kg + base;
    const float* vp = vg + base;
    const float* wp = wg + base;

    float kA[UU], vA[UU], wA[UU];
    float kB[UU], vB[UU], wB[UU];

#pragma unroll
    for (int j = 0; j < UU; ++j) {
        const size_t off = (size_t)j * DD;
        kA[j] = kp[off]; vA[j] = vp[off]; wA[j] = wp[off];
    }

    float P = 1.0f, A = 0.0f, Bv = 0.0f;

    for (int t0 = 0; t0 < LL; t0 += 2 * UU) {
#pragma unroll
        for (int j = 0; j < UU; ++j) {
            const size_t off = (size_t)(t0 + UU + j) * DD;
            kB[j] = kp[off]; vB[j] = vp[off]; wB[j] = wp[off];
        }
#pragma unroll
        for (int j = 0; j < UU; ++j) {
            const float ew = __expf(wA[j]);
            const float ek = __expf(kA[j]);
            P  = P * ew;
            A  = ew * A  + ek;
            Bv = ew * Bv + ek * vA[j];
        }
        if (t0 + 2 * UU < LL) {
#pragma unroll
            for (int j = 0; j < UU; ++j) {
                const size_t off = (size_t)(t0 + 2 * UU + j) * DD;
                kA[j] = kp[off]; vA[j] = vp[off]; wA[j] = wp[off];
            }
        }
#pragma unroll
        for (int j = 0; j < UU; ++j) {
            const float ew = __expf(wB[j]);
            const float ek = __expf(kB[j]);
            P  = P * ew;
            A  = ew * A  + ek;
            Bv = ew * Bv + ek * vB[j];
        }
    }

    const int idx = ch * BDCH + g;   // [NC][BD] layout -> coalesced
    wsP[idx] = P;
    wsA[idx] = A;
    wsB[idx] = Bv;
}

// ---------------------------------------------------------------------------
// K3: fold preceding chunk summaries into carry-in, re-stream chunk, write out
// ---------------------------------------------------------------------------
__global__ __launch_bounds__(NTH) void wkv_final(const float* __restrict__ kg,
                                                 const float* __restrict__ vg,
                                                 const float* __restrict__ wg,
                                                 float* __restrict__ og,
                                                 const float* __restrict__ wsP,
                                                 const float* __restrict__ wsA,
                                                 const float* __restrict__ wsB) {
    const int g  = blockIdx.x * NTH + threadIdx.x;
    const int ch = blockIdx.y;
    const size_t base = (size_t)(g >> 10) * (size_t)TT * DD
                      + (size_t)ch * LL * DD
                      + (size_t)(g & (DD - 1));
    const float* kp = kg + base;
    const float* vp = vg + base;
    const float* wp = wg + base;
    float*       op = og + base;

    // carry-in from chunks [0, ch): <= 15 iterations, coalesced, L2/L3-hot
    float a = 0.0f, b = 0.0f;
    for (int cc = 0; cc < ch; ++cc) {
        const int idx = cc * BDCH + g;
        const float P = wsP[idx];
        a = P * a + wsA[idx];
        b = P * b + wsB[idx];
    }

    float kA[UU], vA[UU], wA[UU];
    float kB[UU], vB[UU], wB[UU];

#pragma unroll
    for (int j = 0; j < UU; ++j) {
        const size_t off = (size_t)j * DD;
        kA[j] = kp[off]; vA[j] = vp[off]; wA[j] = wp[off];
    }

    for (int t0 = 0; t0 < LL; t0 += 2 * UU) {
#pragma unroll
        for (int j = 0; j < UU; ++j) {
            const size_t off = (size_t)(t0 + UU + j) * DD;
            kB[j] = kp[off]; vB[j] = vp[off]; wB[j] = wp[off];
        }
#pragma unroll
        for (int j = 0; j < UU; ++j) {
            const float ew = __expf(wA[j]);
            const float ek = __expf(kA[j]);
            a = ew * a + ek;
            b = ew * b + ek * vA[j];
            op[(size_t)(t0 + j) * DD] = __fdividef(b, a);
        }
        if (t0 + 2 * UU < LL) {
#pragma unroll
            for (int j = 0; j < UU; ++j) {
                const size_t off = (size_t)(t0 + 2 * UU + j) * DD;
                kA[j] = kp[off]; vA[j] = vp[off]; wA[j] = wp[off];
            }
        }
#pragma unroll
        for (int j = 0; j < UU; ++j) {
            const float ew = __expf(wB[j]);
            const float ek = __expf(kB[j]);
            a = ew * a + ek;
            b = ew * b + ek * vB[j];
            op[(size_t)(t0 + UU + j) * DD] = __fdividef(b, a);
        }
    }
}

// ---------------------------------------------------------------------------
// Fallback: original single-pass serial kernel (used only if ws too small)
// ---------------------------------------------------------------------------
__global__ __launch_bounds__(64) void wkv_fwd(const float* __restrict__ kg,
                                              const float* __restrict__ vg,
                                              const float* __restrict__ wg,
                                              float* __restrict__ og) {
    const int c = blockIdx.x * 64 + threadIdx.x;
    const size_t base = (size_t)(c >> 10) * (size_t)TT * DD
                      + (size_t)(c & (DD - 1));
    const float* kp = kg + base;
    const float* vp = vg + base;
    const float* wp = wg + base;
    float*       op = og + base;

    float kA[16], vA[16], wA[16];
    float kB[16], vB[16], wB[16];

#pragma unroll
    for (int j = 0; j < 16; ++j) {
        const size_t off = (size_t)j * DD;
        kA[j] = kp[off]; vA[j] = vp[off]; wA[j] = wp[off];
    }

    float a = 0.0f, b = 0.0f;

    for (int t0 = 0; t0 < TT; t0 += 32) {
#pragma unroll
        for (int j = 0; j < 16; ++j) {
            const size_t off = (size_t)(t0 + 16 + j) * DD;
            kB[j] = kp[off]; vB[j] = vp[off]; wB[j] = wp[off];
        }
#pragma unroll
        for (int j = 0; j < 16; ++j) {
            const float ew = __expf(wA[j]);
            const float ek = __expf(kA[j]);
            a = ew * a + ek;
            b = ew * b + ek * vA[j];
            op[(size_t)(t0 + j) * DD] = __fdividef(b, a);
        }
        if (t0 + 32 < TT) {
#pragma unroll
            for (int j = 0; j < 16; ++j) {
                const size_t off = (size_t)(t0 + 32 + j) * DD;
                kA[j] = kp[off]; vA[j] = vp[off]; wA[j] = wp[off];
            }
        }
#pragma unroll
        for (int j = 0; j < 16; ++j) {
            const float ew = __expf(wB[j]);
            const float ek = __expf(kB[j]);
            a = ew * a + ek;
            b = ew * b + ek * vB[j];
            op[(size_t)(t0 + 16 + j) * DD] = __fdividef(b, a);
        }
    }
}

extern "C" void kernel_launch(void* const* d_in, const int* in_sizes, int n_in,
                              void* d_out, int out_size, void* d_ws, size_t ws_size,
                              hipStream_t stream) {
    const float* k = (const float*)d_in[0];
    const float* v = (const float*)d_in[1];
    const float* w = (const float*)d_in[2];
    float* out = (float*)d_out;

    const size_t need = (size_t)3 * NC * BDCH * sizeof(float);   // 3 MB
    if (d_ws != nullptr && ws_size >= need) {
        float* wsP = (float*)d_ws;
        float* wsA = wsP + (size_t)NC * BDCH;
        float* wsB = wsA + (size_t)NC * BDCH;
        dim3 grid(BDCH / NTH, NC);
        wkv_part<<<grid, dim3(NTH), 0, stream>>>(k, v, w, wsP, wsA, wsB);
        wkv_final<<<grid, dim3(NTH), 0, stream>>>(k, v, w, out, wsP, wsA, wsB);
    } else {
        wkv_fwd<<<dim3(BDCH / 64), dim3(64), 0, stream>>>(k, v, w, out);
    }
}

// Round 2
// 476.210 us; speedup vs baseline: 1.0201x; 1.0140x over previous
//
#include <hip/hip_runtime.h>

// RWKV WKV forward scan, chunk-parallel two-pass, float4 formulation.
// B=16, T=2048, D=1024, fp32.
//
// Round-1 lesson: occupancy 2.9%->37.6% moved BW only 1.39->1.52 TB/s; the
// limiter is per-VMEM-instruction request granularity (scalar dword loads =
// 256 B/wave-instr vs the 6.3 TB/s ceiling measured with float4 = 1 KB/instr).
// This version: each thread owns 4 consecutive channels -> all global traffic
// is float4, and each 256-thread block covers the full D of one batch row, so
// every block streams a CONTIGUOUS L*4KB region per array (ideal DRAM bursts).
//
// K1: per-(b,chunk) block computes 4-wide chunk summaries (P,A,B) -> 6 MB ws.
// K3: folds preceding summaries (<=31 pipelined float4 loads, L2/L3-hot) into
//     the carry, re-streams the chunk, writes contiguous float4 outputs.

#define TT 2048
#define DD 1024
#define BB 16
#define NC 32
#define LL (TT / NC)            // 64 steps per chunk
#define NTH 256                 // = DD/4 -> one block covers one b fully
#define NG (BB * (DD / 4))      // 4096 float4 chain-groups
#define UU 4                    // prefetch batch (double-buffered)

__device__ __forceinline__ float4 f4_fold(float4 P, float4 s, float4 add) {
    return make_float4(fmaf(P.x, s.x, add.x), fmaf(P.y, s.y, add.y),
                       fmaf(P.z, s.z, add.z), fmaf(P.w, s.w, add.w));
}

// one recurrence step on one component, chunk-summary form (tracks P)
#define K1_STEP_C(c, kk, vv, ww)                                           \
    do {                                                                   \
        const float ew = __expf(ww.c);                                     \
        const float ek = __expf(kk.c);                                     \
        P.c *= ew;                                                         \
        A.c = fmaf(ew, A.c, ek);                                           \
        Bv.c = fmaf(ew, Bv.c, ek * vv.c);                                  \
    } while (0)
#define K1_STEP(kk, vv, ww)                                                \
    {                                                                      \
        K1_STEP_C(x, kk, vv, ww);                                          \
        K1_STEP_C(y, kk, vv, ww);                                          \
        K1_STEP_C(z, kk, vv, ww);                                          \
        K1_STEP_C(w, kk, vv, ww);                                          \
    }

// one recurrence step on one component, output form
#define K3_STEP_C(c, kk, vv, ww, oo)                                       \
    do {                                                                   \
        const float ew = __expf(ww.c);                                     \
        const float ek = __expf(kk.c);                                     \
        a.c = fmaf(ew, a.c, ek);                                           \
        bv.c = fmaf(ew, bv.c, ek * vv.c);                                  \
        oo.c = __fdividef(bv.c, a.c);                                      \
    } while (0)
#define K3_STEP(kk, vv, ww, oo)                                            \
    {                                                                      \
        K3_STEP_C(x, kk, vv, ww, oo);                                      \
        K3_STEP_C(y, kk, vv, ww, oo);                                      \
        K3_STEP_C(z, kk, vv, ww, oo);                                      \
        K3_STEP_C(w, kk, vv, ww, oo);                                      \
    }

// ---------------------------------------------------------------------------
// K1: chunk summaries. grid (BB, NC-1) -- last chunk's summary is never used.
// ---------------------------------------------------------------------------
__global__ __launch_bounds__(NTH) void wkv_part(const float* __restrict__ kg,
                                                const float* __restrict__ vg,
                                                const float* __restrict__ wg,
                                                float4* __restrict__ wsP,
                                                float4* __restrict__ wsA,
                                                float4* __restrict__ wsB) {
    const int b = blockIdx.x;
    const int ch = blockIdx.y;
    const size_t base = ((size_t)b * TT + (size_t)ch * LL) * DD + threadIdx.x * 4;
    const float4* kp = (const float4*)(kg + base);
    const float4* vp = (const float4*)(vg + base);
    const float4* wp = (const float4*)(wg + base);
    const int S = DD / 4;  // float4 stride per t-step

    float4 kA[UU], vA[UU], wA[UU], kB[UU], vB[UU], wB[UU];

#pragma unroll
    for (int j = 0; j < UU; ++j) {
        kA[j] = kp[(size_t)j * S];
        vA[j] = vp[(size_t)j * S];
        wA[j] = wp[(size_t)j * S];
    }

    float4 P = make_float4(1.f, 1.f, 1.f, 1.f);
    float4 A = make_float4(0.f, 0.f, 0.f, 0.f);
    float4 Bv = make_float4(0.f, 0.f, 0.f, 0.f);

    for (int t0 = 0; t0 < LL; t0 += 2 * UU) {
#pragma unroll
        for (int j = 0; j < UU; ++j) {
            const size_t off = (size_t)(t0 + UU + j) * S;
            kB[j] = kp[off]; vB[j] = vp[off]; wB[j] = wp[off];
        }
#pragma unroll
        for (int j = 0; j < UU; ++j) { K1_STEP(kA[j], vA[j], wA[j]); }
        if (t0 + 2 * UU < LL) {
#pragma unroll
            for (int j = 0; j < UU; ++j) {
                const size_t off = (size_t)(t0 + 2 * UU + j) * S;
                kA[j] = kp[off]; vA[j] = vp[off]; wA[j] = wp[off];
            }
        }
#pragma unroll
        for (int j = 0; j < UU; ++j) { K1_STEP(kB[j], vB[j], wB[j]); }
    }

    const int g = b * (DD / 4) + threadIdx.x;  // [NC][NG] layout, coalesced
    wsP[ch * NG + g] = P;
    wsA[ch * NG + g] = A;
    wsB[ch * NG + g] = Bv;
}

// ---------------------------------------------------------------------------
// K3: fold carry, re-stream chunk, write outputs. grid (BB, NC).
// ---------------------------------------------------------------------------
__global__ __launch_bounds__(NTH) void wkv_final(const float* __restrict__ kg,
                                                 const float* __restrict__ vg,
                                                 const float* __restrict__ wg,
                                                 float* __restrict__ og,
                                                 const float4* __restrict__ wsP,
                                                 const float4* __restrict__ wsA,
                                                 const float4* __restrict__ wsB) {
    const int b = blockIdx.x;
    const int ch = blockIdx.y;
    const size_t base = ((size_t)b * TT + (size_t)ch * LL) * DD + threadIdx.x * 4;
    const float4* kp = (const float4*)(kg + base);
    const float4* vp = (const float4*)(vg + base);
    const float4* wp = (const float4*)(wg + base);
    float4* op = (float4*)(og + base);
    const int S = DD / 4;
    const int g = b * (DD / 4) + threadIdx.x;

    // carry-in: fold summaries of chunks [0, ch), 2-deep software pipeline
    float4 a = make_float4(0.f, 0.f, 0.f, 0.f);
    float4 bv = make_float4(0.f, 0.f, 0.f, 0.f);
    if (ch > 0) {
        float4 Pc = wsP[g], Ac = wsA[g], Bc = wsB[g];
        for (int cc = 1; cc < ch; ++cc) {
            const float4 Pn = wsP[cc * NG + g];
            const float4 An = wsA[cc * NG + g];
            const float4 Bn = wsB[cc * NG + g];
            a = f4_fold(Pc, a, Ac);
            bv = f4_fold(Pc, bv, Bc);
            Pc = Pn; Ac = An; Bc = Bn;
        }
        a = f4_fold(Pc, a, Ac);
        bv = f4_fold(Pc, bv, Bc);
    }

    float4 kA[UU], vA[UU], wA[UU], kB[UU], vB[UU], wB[UU];

#pragma unroll
    for (int j = 0; j < UU; ++j) {
        kA[j] = kp[(size_t)j * S];
        vA[j] = vp[(size_t)j * S];
        wA[j] = wp[(size_t)j * S];
    }

    for (int t0 = 0; t0 < LL; t0 += 2 * UU) {
#pragma unroll
        for (int j = 0; j < UU; ++j) {
            const size_t off = (size_t)(t0 + UU + j) * S;
            kB[j] = kp[off]; vB[j] = vp[off]; wB[j] = wp[off];
        }
#pragma unroll
        for (int j = 0; j < UU; ++j) {
            float4 o;
            K3_STEP(kA[j], vA[j], wA[j], o);
            op[(size_t)(t0 + j) * S] = o;
        }
        if (t0 + 2 * UU < LL) {
#pragma unroll
            for (int j = 0; j < UU; ++j) {
                const size_t off = (size_t)(t0 + 2 * UU + j) * S;
                kA[j] = kp[off]; vA[j] = vp[off]; wA[j] = wp[off];
            }
        }
#pragma unroll
        for (int j = 0; j < UU; ++j) {
            float4 o;
            K3_STEP(kB[j], vB[j], wB[j], o);
            op[(size_t)(t0 + UU + j) * S] = o;
        }
    }
}

// ---------------------------------------------------------------------------
// Fallback: serial single-pass kernel (used only if ws too small)
// ---------------------------------------------------------------------------
__global__ __launch_bounds__(64) void wkv_fwd(const float* __restrict__ kg,
                                              const float* __restrict__ vg,
                                              const float* __restrict__ wg,
                                              float* __restrict__ og) {
    const int c = blockIdx.x * 64 + threadIdx.x;
    const size_t base = (size_t)(c >> 10) * (size_t)TT * DD + (size_t)(c & (DD - 1));
    const float* kp = kg + base;
    const float* vp = vg + base;
    const float* wp = wg + base;
    float* op = og + base;

    float a = 0.0f, b = 0.0f;
    for (int t = 0; t < TT; ++t) {
        const float ew = __expf(wp[(size_t)t * DD]);
        const float ek = __expf(kp[(size_t)t * DD]);
        a = ew * a + ek;
        b = ew * b + ek * vp[(size_t)t * DD];
        op[(size_t)t * DD] = __fdividef(b, a);
    }
}

extern "C" void kernel_launch(void* const* d_in, const int* in_sizes, int n_in,
                              void* d_out, int out_size, void* d_ws, size_t ws_size,
                              hipStream_t stream) {
    const float* k = (const float*)d_in[0];
    const float* v = (const float*)d_in[1];
    const float* w = (const float*)d_in[2];
    float* out = (float*)d_out;

    const size_t need = (size_t)3 * NC * NG * sizeof(float4);  // 6 MB
    if (d_ws != nullptr && ws_size >= need) {
        float4* wsP = (float4*)d_ws;
        float4* wsA = wsP + (size_t)NC * NG;
        float4* wsB = wsA + (size_t)NC * NG;
        wkv_part<<<dim3(BB, NC - 1), dim3(NTH), 0, stream>>>(k, v, w, wsP, wsA, wsB);
        wkv_final<<<dim3(BB, NC), dim3(NTH), 0, stream>>>(k, v, w, out, wsP, wsA, wsB);
    } else {
        wkv_fwd<<<dim3((BB * DD) / 64), dim3(64), 0, stream>>>(k, v, w, out);
    }
}